// Round 3
// baseline (387.305 us; speedup 1.0000x reference)
//
#include <hip/hip_runtime.h>

#define BATCH 16
#define CDIM 512
#define SEQ 1024
#define NHEAD 4
#define HDIM 128
#define NPB (CDIM*SEQ)
#define GN_EPS 1e-5f
#define ATT_SCALE 0.08838834764831845f
#define MQ (BATCH*SEQ)        // 16384 rows
#define NQKV (3*CDIM)         // 1536

typedef __attribute__((ext_vector_type(8))) short bf16x8;
typedef __attribute__((ext_vector_type(4))) float f32x4;

__device__ __forceinline__ unsigned short f2bf(float f) {
    unsigned int u = __float_as_uint(f);
    unsigned int r = (u + 0x7fffu + ((u >> 16) & 1u)) >> 16;
    return (unsigned short)r;
}
__device__ __forceinline__ float bf2f(unsigned short h) {
    return __uint_as_float(((unsigned int)h) << 16);
}
// async global->LDS, 16B per lane; LDS dest = uniform base + lane*16
__device__ __forceinline__ void gld16(const unsigned short* g, unsigned short* l) {
    __builtin_amdgcn_global_load_lds(
        (const __attribute__((address_space(1))) void*)g,
        (__attribute__((address_space(3))) void*)l, 16, 0, 0);
}

// ---------------------------------------------------------------------------
// K1: GroupNorm stats (sum, sumsq per batch)
// ---------------------------------------------------------------------------
__global__ __launch_bounds__(256) void gn_stats(const float* __restrict__ x,
                                                float* __restrict__ stats) {
    int b = blockIdx.x >> 4;
    int part = blockIdx.x & 15;
    const float4* xp = (const float4*)(x + (size_t)b*NPB + (size_t)part*(NPB/16));
    float sum = 0.f, ssq = 0.f;
#pragma unroll
    for (int i = 0; i < 32; ++i) {
        float4 v = xp[threadIdx.x + i*256];
        sum += v.x + v.y + v.z + v.w;
        ssq += v.x*v.x + v.y*v.y + v.z*v.z + v.w*v.w;
    }
#pragma unroll
    for (int off = 1; off < 64; off <<= 1) {
        sum += __shfl_xor(sum, off);
        ssq += __shfl_xor(ssq, off);
    }
    __shared__ float ls[8];
    int wave = threadIdx.x >> 6, lane = threadIdx.x & 63;
    if (lane == 0) { ls[wave*2] = sum; ls[wave*2+1] = ssq; }
    __syncthreads();
    if (threadIdx.x == 0) {
        atomicAdd(&stats[b*2+0], ls[0]+ls[2]+ls[4]+ls[6]);
        atomicAdd(&stats[b*2+1], ls[1]+ls[3]+ls[5]+ls[7]);
    }
}

// ---------------------------------------------------------------------------
// K2: split fp32 weights into bf16 hi/lo
// ---------------------------------------------------------------------------
__global__ __launch_bounds__(256) void split_w(const float* __restrict__ in,
                                               unsigned short* __restrict__ hi,
                                               unsigned short* __restrict__ lo) {
    int i = blockIdx.x*256 + threadIdx.x;
    float4 v = ((const float4*)in)[i];
    ushort4 h, l;
    h.x = f2bf(v.x); l.x = f2bf(v.x - bf2f(h.x));
    h.y = f2bf(v.y); l.y = f2bf(v.y - bf2f(h.y));
    h.z = f2bf(v.z); l.z = f2bf(v.z - bf2f(h.z));
    h.w = f2bf(v.w); l.w = f2bf(v.w - bf2f(h.w));
    ((ushort4*)hi)[i] = h;
    ((ushort4*)lo)[i] = l;
}

// ---------------------------------------------------------------------------
// K3: A = GroupNorm(x) transposed to [b*s][c], split hi/lo (32x32 LDS tile)
// ---------------------------------------------------------------------------
__global__ __launch_bounds__(256) void prep_a(const float* __restrict__ x,
                                              const float* __restrict__ stats,
                                              const float* __restrict__ gnw,
                                              const float* __restrict__ gnb,
                                              unsigned short* __restrict__ Ahi,
                                              unsigned short* __restrict__ Alo) {
    __shared__ float Ls[32][33];
    const int b = blockIdx.z;
    const int c0 = blockIdx.y * 32;
    const int s0 = blockIdx.x * 32;
    const int tx = threadIdx.x & 31, ty = threadIdx.x >> 5;
    float sum = stats[b*2+0], ssq = stats[b*2+1];
    float mean = sum * (1.f/NPB);
    float var  = ssq * (1.f/NPB) - mean*mean;
    float istd = rsqrtf(var + GN_EPS);
#pragma unroll
    for (int i = 0; i < 4; ++i) {
        int cc = ty + 8*i;
        Ls[cc][tx] = x[((size_t)b*CDIM + c0 + cc)*SEQ + s0 + tx];
    }
    __syncthreads();
    int c = c0 + tx;
    float g  = gnw[c] * istd;
    float sh = gnb[c] - mean * g;
#pragma unroll
    for (int i = 0; i < 4; ++i) {
        int ss = ty + 8*i;
        float v = Ls[tx][ss] * g + sh;
        unsigned short h = f2bf(v);
        size_t idx = ((size_t)b*SEQ + s0 + ss)*CDIM + c;
        Ahi[idx] = h;
        Alo[idx] = f2bf(v - bf2f(h));
    }
}

// ---------------------------------------------------------------------------
// K4: QKV GEMM, split-bf16 MFMA, global_load_lds staging (linear LDS tiles).
// C[m][n] = A[m][k] . W[n][k] + bias.  128x128x32 tile, 4 waves, 64x64/wave.
// ---------------------------------------------------------------------------
__global__ __launch_bounds__(256, 2) void gemm_qkv(
    const unsigned short* __restrict__ Ahi, const unsigned short* __restrict__ Alo,
    const unsigned short* __restrict__ Bhi, const unsigned short* __restrict__ Blo,
    const float* __restrict__ bias,
    unsigned short* __restrict__ Chi, unsigned short* __restrict__ Clo)
{
    __shared__ __align__(16) unsigned short As[2][128][32];
    __shared__ __align__(16) unsigned short Bs[2][128][32];
    const int n0 = blockIdx.x * 128;
    const int m0 = blockIdx.y * 128;
    const int t = threadIdx.x;
    const int w = t >> 6, l = t & 63, g = l >> 4, lm = l & 15;
    const int wm = (w & 1) * 64, wn = (w >> 1) * 64;
    f32x4 acc[4][4] = {};

    // wave w stages one array: 0->As hi, 1->As lo, 2->Bs hi, 3->Bs lo
    const unsigned short* src = (w==0)?Ahi:(w==1)?Alo:(w==2)?Bhi:Blo;
    unsigned short (*dst)[32] = (w==0)?As[0]:(w==1)?As[1]:(w==2)?Bs[0]:Bs[1];
    const int rb = (w < 2) ? m0 : n0;
    const int srow = l >> 2, schk = (l & 3) * 8;

    for (int k0 = 0; k0 < CDIM; k0 += 32) {
        __syncthreads();
#pragma unroll
        for (int i = 0; i < 8; ++i)
            gld16(src + (size_t)(rb + i*16 + srow)*CDIM + k0 + schk, &dst[i*16][0]);
        __syncthreads();
        bf16x8 ah[4], al[4], bh[4], bl[4];
#pragma unroll
        for (int mi = 0; mi < 4; ++mi) {
            ah[mi] = *(const bf16x8*)&As[0][wm + mi*16 + lm][g*8];
            al[mi] = *(const bf16x8*)&As[1][wm + mi*16 + lm][g*8];
        }
#pragma unroll
        for (int ni = 0; ni < 4; ++ni) {
            bh[ni] = *(const bf16x8*)&Bs[0][wn + ni*16 + lm][g*8];
            bl[ni] = *(const bf16x8*)&Bs[1][wn + ni*16 + lm][g*8];
        }
#pragma unroll
        for (int mi = 0; mi < 4; ++mi)
#pragma unroll
            for (int ni = 0; ni < 4; ++ni) {
                acc[mi][ni] = __builtin_amdgcn_mfma_f32_16x16x32_bf16(ah[mi], bh[ni], acc[mi][ni], 0, 0, 0);
                acc[mi][ni] = __builtin_amdgcn_mfma_f32_16x16x32_bf16(ah[mi], bl[ni], acc[mi][ni], 0, 0, 0);
                acc[mi][ni] = __builtin_amdgcn_mfma_f32_16x16x32_bf16(al[mi], bh[ni], acc[mi][ni], 0, 0, 0);
            }
    }
#pragma unroll
    for (int mi = 0; mi < 4; ++mi)
#pragma unroll
        for (int ni = 0; ni < 4; ++ni) {
            int n = n0 + wn + ni*16 + lm;
            float bv = bias[n];
#pragma unroll
            for (int r = 0; r < 4; ++r) {
                int m = m0 + wm + mi*16 + 4*g + r;
                float v = acc[mi][ni][r] + bv;
                unsigned short h = f2bf(v);
                size_t idx = (size_t)m*NQKV + n;
                Chi[idx] = h;
                Clo[idx] = f2bf(v - bf2f(h));
            }
        }
}

// ---------------------------------------------------------------------------
// K5: transpose V-part of QKV -> VT[b][h][d][s], bf16 hi/lo
// ---------------------------------------------------------------------------
__global__ __launch_bounds__(256) void prep_vt(
    const unsigned short* __restrict__ QKVhi, const unsigned short* __restrict__ QKVlo,
    unsigned short* __restrict__ VThi, unsigned short* __restrict__ VTlo)
{
    __shared__ unsigned short Ts[2][32][34];
    const int s0 = blockIdx.x * 32;
    const int d0 = blockIdx.y * 32;
    const int bh = blockIdx.z;
    const int b = bh >> 2, h = bh & 3;
    const int tx = threadIdx.x & 31, ty = threadIdx.x >> 5;
#pragma unroll
    for (int i = 0; i < 4; ++i) {
        int ss = ty + 8*i;
        size_t src = ((size_t)b*SEQ + s0 + ss)*NQKV + 2*CDIM + h*HDIM + d0 + tx;
        Ts[0][ss][tx] = QKVhi[src];
        Ts[1][ss][tx] = QKVlo[src];
    }
    __syncthreads();
#pragma unroll
    for (int i = 0; i < 4; ++i) {
        int dd = ty + 8*i;
        size_t dst = ((size_t)bh*HDIM + d0 + dd)*SEQ + s0 + tx;
        VThi[dst] = Ts[0][tx][dd];
        VTlo[dst] = Ts[1][tx][dd];
    }
}

// ---------------------------------------------------------------------------
// K6: flash attention, split-bf16 MFMA, global_load_lds K/V staging.
// K in LDS as [hi/lo][kb][32 kv][32 k-within] subtiles; V as [hi/lo][128 d][32 kv].
// ---------------------------------------------------------------------------
__global__ __launch_bounds__(256, 2) void attn(
    const unsigned short* __restrict__ QKVhi, const unsigned short* __restrict__ QKVlo,
    const unsigned short* __restrict__ VThi,  const unsigned short* __restrict__ VTlo,
    unsigned short* __restrict__ Ohi, unsigned short* __restrict__ Olo)
{
    __shared__ __align__(16) unsigned short Ks[2][4][32][32];
    __shared__ __align__(16) unsigned short Vs[2][128][32];
    __shared__ __align__(16) unsigned short Ps[4][2][32][40];
    const int qt = blockIdx.x, h = blockIdx.y, b = blockIdx.z;
    const int t = threadIdx.x;
    const int w = t >> 6, l = t & 63, g = l >> 4, lm = l & 15;
    const int mq = b*SEQ + qt*128 + w*32;

    bf16x8 qh[2][4], ql[2][4];
#pragma unroll
    for (int mi = 0; mi < 2; ++mi)
#pragma unroll
        for (int kb = 0; kb < 4; ++kb) {
            size_t idx = (size_t)(mq + mi*16 + lm)*NQKV + h*HDIM + kb*32 + g*8;
            qh[mi][kb] = *(const bf16x8*)&QKVhi[idx];
            ql[mi][kb] = *(const bf16x8*)&QKVlo[idx];
        }

    f32x4 oacc[2][8] = {};
    float mrun[2][4], lrun[2][4];
#pragma unroll
    for (int mi = 0; mi < 2; ++mi)
#pragma unroll
        for (int r = 0; r < 4; ++r) { mrun[mi][r] = -INFINITY; lrun[mi][r] = 0.f; }

    const int srow = l >> 2, schk = (l & 3) * 8;

    for (int kt = 0; kt < 32; ++kt) {
        __syncthreads();
        if (w < 2) {      // stage K: wave 0 -> hi, wave 1 -> lo
            const unsigned short* src = (w == 0) ? QKVhi : QKVlo;
#pragma unroll
            for (int i = 0; i < 8; ++i) {
                int kb = i >> 1, half = i & 1;
                int row = half*16 + srow;
                gld16(src + (size_t)(b*SEQ + kt*32 + row)*NQKV + CDIM + h*HDIM + kb*32 + schk,
                      &Ks[w][kb][half*16][0]);
            }
        } else {          // stage V: wave 2 -> hi, wave 3 -> lo
            const unsigned short* src = (w == 2) ? VThi : VTlo;
#pragma unroll
            for (int i = 0; i < 8; ++i)
                gld16(src + ((size_t)(b*NHEAD + h)*HDIM + i*16 + srow)*SEQ + kt*32 + schk,
                      &Vs[w-2][i*16][0]);
        }
        __syncthreads();

        // QK^T : S[32 q][32 kv]
        f32x4 sacc[2][2] = {};
#pragma unroll
        for (int kb = 0; kb < 4; ++kb) {
            bf16x8 kh[2], kl[2];
#pragma unroll
            for (int nf = 0; nf < 2; ++nf) {
                kh[nf] = *(const bf16x8*)&Ks[0][kb][nf*16 + lm][g*8];
                kl[nf] = *(const bf16x8*)&Ks[1][kb][nf*16 + lm][g*8];
            }
#pragma unroll
            for (int mi = 0; mi < 2; ++mi)
#pragma unroll
                for (int nf = 0; nf < 2; ++nf) {
                    sacc[mi][nf] = __builtin_amdgcn_mfma_f32_16x16x32_bf16(qh[mi][kb], kh[nf], sacc[mi][nf], 0, 0, 0);
                    sacc[mi][nf] = __builtin_amdgcn_mfma_f32_16x16x32_bf16(qh[mi][kb], kl[nf], sacc[mi][nf], 0, 0, 0);
                    sacc[mi][nf] = __builtin_amdgcn_mfma_f32_16x16x32_bf16(ql[mi][kb], kh[nf], sacc[mi][nf], 0, 0, 0);
                }
        }
        float pmax[2][4];
#pragma unroll
        for (int mi = 0; mi < 2; ++mi)
#pragma unroll
            for (int r = 0; r < 4; ++r) {
                sacc[mi][0][r] *= ATT_SCALE;
                sacc[mi][1][r] *= ATT_SCALE;
                pmax[mi][r] = fmaxf(sacc[mi][0][r], sacc[mi][1][r]);
            }
#pragma unroll
        for (int off = 1; off < 16; off <<= 1)
#pragma unroll
            for (int mi = 0; mi < 2; ++mi)
#pragma unroll
                for (int r = 0; r < 4; ++r)
                    pmax[mi][r] = fmaxf(pmax[mi][r], __shfl_xor(pmax[mi][r], off));
        float cor[2][4];
#pragma unroll
        for (int mi = 0; mi < 2; ++mi)
#pragma unroll
            for (int r = 0; r < 4; ++r) {
                float nm = fmaxf(mrun[mi][r], pmax[mi][r]);
                cor[mi][r] = __expf(mrun[mi][r] - nm);
                mrun[mi][r] = nm;
                lrun[mi][r] *= cor[mi][r];
            }
#pragma unroll
        for (int mi = 0; mi < 2; ++mi)
#pragma unroll
            for (int nd = 0; nd < 8; ++nd)
#pragma unroll
                for (int r = 0; r < 4; ++r)
                    oacc[mi][nd][r] *= cor[mi][r];
        float psum[2][4] = {};
#pragma unroll
        for (int mi = 0; mi < 2; ++mi)
#pragma unroll
            for (int nf = 0; nf < 2; ++nf)
#pragma unroll
                for (int r = 0; r < 4; ++r) {
                    float p = __expf(sacc[mi][nf][r] - mrun[mi][r]);
                    psum[mi][r] += p;
                    unsigned short ph = f2bf(p);
                    int q = mi*16 + 4*g + r, kv = nf*16 + lm;
                    Ps[w][0][q][kv] = ph;
                    Ps[w][1][q][kv] = f2bf(p - bf2f(ph));
                }
#pragma unroll
        for (int off = 1; off < 16; off <<= 1)
#pragma unroll
            for (int mi = 0; mi < 2; ++mi)
#pragma unroll
                for (int r = 0; r < 4; ++r)
                    psum[mi][r] += __shfl_xor(psum[mi][r], off);
#pragma unroll
        for (int mi = 0; mi < 2; ++mi)
#pragma unroll
            for (int r = 0; r < 4; ++r)
                lrun[mi][r] += psum[mi][r];

        // PV (same-wave LDS write->read fence, rule #18)
        asm volatile("s_waitcnt lgkmcnt(0)" ::: "memory");
        __builtin_amdgcn_sched_barrier(0);
        bf16x8 ph[2], pl[2];
#pragma unroll
        for (int mi = 0; mi < 2; ++mi) {
            ph[mi] = *(const bf16x8*)&Ps[w][0][mi*16 + lm][g*8];
            pl[mi] = *(const bf16x8*)&Ps[w][1][mi*16 + lm][g*8];
        }
#pragma unroll
        for (int nd = 0; nd < 8; ++nd) {
            bf16x8 vh = *(const bf16x8*)&Vs[0][nd*16 + lm][g*8];
            bf16x8 vl = *(const bf16x8*)&Vs[1][nd*16 + lm][g*8];
#pragma unroll
            for (int mi = 0; mi < 2; ++mi) {
                oacc[mi][nd] = __builtin_amdgcn_mfma_f32_16x16x32_bf16(ph[mi], vh, oacc[mi][nd], 0, 0, 0);
                oacc[mi][nd] = __builtin_amdgcn_mfma_f32_16x16x32_bf16(ph[mi], vl, oacc[mi][nd], 0, 0, 0);
                oacc[mi][nd] = __builtin_amdgcn_mfma_f32_16x16x32_bf16(pl[mi], vh, oacc[mi][nd], 0, 0, 0);
            }
        }
    }
#pragma unroll
    for (int mi = 0; mi < 2; ++mi)
#pragma unroll
        for (int r = 0; r < 4; ++r) {
            float inv = 1.f / lrun[mi][r];
#pragma unroll
            for (int nd = 0; nd < 8; ++nd) {
                float v = oacc[mi][nd][r] * inv;
                int m = mq + mi*16 + 4*g + r;
                int col = h*HDIM + nd*16 + lm;
                unsigned short hh = f2bf(v);
                size_t idx = (size_t)m*CDIM + col;
                Ohi[idx] = hh;
                Olo[idx] = f2bf(v - bf2f(hh));
            }
        }
}

// ---------------------------------------------------------------------------
// K7: output projection, transposed: out^T[c][m] = W[c][k] . O[m][k];
// coalesced [b][c][s] store with fused bias + residual.
// ---------------------------------------------------------------------------
__global__ __launch_bounds__(256, 2) void out_gemm(
    const unsigned short* __restrict__ Whi, const unsigned short* __restrict__ Wlo,
    const unsigned short* __restrict__ Ohi, const unsigned short* __restrict__ Olo,
    const float* __restrict__ bias, const float* __restrict__ x,
    float* __restrict__ out)
{
    __shared__ __align__(16) unsigned short As[2][128][32];
    __shared__ __align__(16) unsigned short Bs[2][128][32];
    const int m0 = blockIdx.x * 128;
    const int c0 = blockIdx.y * 128;
    const int t = threadIdx.x;
    const int w = t >> 6, l = t & 63, g = l >> 4, lm = l & 15;
    const int wc = (w & 1) * 64, wn = (w >> 1) * 64;
    f32x4 acc[4][4] = {};

    const unsigned short* src = (w==0)?Whi:(w==1)?Wlo:(w==2)?Ohi:Olo;
    unsigned short (*dst)[32] = (w==0)?As[0]:(w==1)?As[1]:(w==2)?Bs[0]:Bs[1];
    const int rb = (w < 2) ? c0 : m0;
    const int srow = l >> 2, schk = (l & 3) * 8;

    for (int k0 = 0; k0 < CDIM; k0 += 32) {
        __syncthreads();
#pragma unroll
        for (int i = 0; i < 8; ++i)
            gld16(src + (size_t)(rb + i*16 + srow)*CDIM + k0 + schk, &dst[i*16][0]);
        __syncthreads();
        bf16x8 ah[4], al[4], bh[4], bl[4];
#pragma unroll
        for (int mi = 0; mi < 4; ++mi) {
            ah[mi] = *(const bf16x8*)&As[0][wc + mi*16 + lm][g*8];
            al[mi] = *(const bf16x8*)&As[1][wc + mi*16 + lm][g*8];
        }
#pragma unroll
        for (int ni = 0; ni < 4; ++ni) {
            bh[ni] = *(const bf16x8*)&Bs[0][wn + ni*16 + lm][g*8];
            bl[ni] = *(const bf16x8*)&Bs[1][wn + ni*16 + lm][g*8];
        }
#pragma unroll
        for (int mi = 0; mi < 4; ++mi)
#pragma unroll
            for (int ni = 0; ni < 4; ++ni) {
                acc[mi][ni] = __builtin_amdgcn_mfma_f32_16x16x32_bf16(ah[mi], bh[ni], acc[mi][ni], 0, 0, 0);
                acc[mi][ni] = __builtin_amdgcn_mfma_f32_16x16x32_bf16(ah[mi], bl[ni], acc[mi][ni], 0, 0, 0);
                acc[mi][ni] = __builtin_amdgcn_mfma_f32_16x16x32_bf16(al[mi], bh[ni], acc[mi][ni], 0, 0, 0);
            }
    }
#pragma unroll
    for (int mi = 0; mi < 4; ++mi)
#pragma unroll
        for (int r = 0; r < 4; ++r) {
            int c = c0 + wc + mi*16 + 4*g + r;
            float bv = bias[c];
#pragma unroll
            for (int ni = 0; ni < 4; ++ni) {
                int m = m0 + wn + ni*16 + lm;
                int bb = m >> 10, s = m & 1023;
                size_t idx = ((size_t)bb*CDIM + c)*SEQ + s;
                out[idx] = x[idx] + acc[mi][ni][r] + bv;
            }
        }
}

// ---------------------------------------------------------------------------
extern "C" void kernel_launch(void* const* d_in, const int* in_sizes, int n_in,
                              void* d_out, int out_size, void* d_ws, size_t ws_size,
                              hipStream_t stream) {
    const float* x    = (const float*)d_in[0];
    const float* gnw  = (const float*)d_in[1];
    const float* gnb  = (const float*)d_in[2];
    const float* qkvw = (const float*)d_in[3];
    const float* qkvb = (const float*)d_in[4];
    const float* outw = (const float*)d_in[5];
    const float* outb = (const float*)d_in[6];
    float* out = (float*)d_out;

    char* wsp = (char*)d_ws;
    size_t off = 0;
    float* stats = (float*)wsp;                 off += 256;
    unsigned short* WhiQ = (unsigned short*)(wsp+off); off += (size_t)NQKV*CDIM*2;
    unsigned short* WloQ = (unsigned short*)(wsp+off); off += (size_t)NQKV*CDIM*2;
    unsigned short* WhiO = (unsigned short*)(wsp+off); off += (size_t)CDIM*CDIM*2;
    unsigned short* WloO = (unsigned short*)(wsp+off); off += (size_t)CDIM*CDIM*2;
    unsigned short* Ahi  = (unsigned short*)(wsp+off); off += (size_t)MQ*CDIM*2;
    unsigned short* Alo  = (unsigned short*)(wsp+off); off += (size_t)MQ*CDIM*2;
    unsigned short* Qhi  = (unsigned short*)(wsp+off); off += (size_t)MQ*NQKV*2;
    unsigned short* Qlo  = (unsigned short*)(wsp+off); off += (size_t)MQ*NQKV*2;
    unsigned short* VThi = (unsigned short*)(wsp+off); off += (size_t)MQ*CDIM*2;
    unsigned short* VTlo = (unsigned short*)(wsp+off); off += (size_t)MQ*CDIM*2;
    unsigned short* Ohi = Ahi;   // A dead after gemm_qkv
    unsigned short* Olo = Alo;

    hipMemsetAsync(stats, 0, 256, stream);
    gn_stats<<<dim3(256), dim3(256), 0, stream>>>(x, stats);
    split_w<<<dim3((NQKV*CDIM)/1024), dim3(256), 0, stream>>>(qkvw, WhiQ, WloQ);
    split_w<<<dim3((CDIM*CDIM)/1024), dim3(256), 0, stream>>>(outw, WhiO, WloO);
    prep_a<<<dim3(32, 16, 16), dim3(256), 0, stream>>>(x, stats, gnw, gnb, Ahi, Alo);
    gemm_qkv<<<dim3(12, 128), dim3(256), 0, stream>>>(Ahi, Alo, WhiQ, WloQ, qkvb, Qhi, Qlo);
    prep_vt<<<dim3(32, 4, 64), dim3(256), 0, stream>>>(Qhi, Qlo, VThi, VTlo);
    attn<<<dim3(8, 4, 16), dim3(256), 0, stream>>>(Qhi, Qlo, VThi, VTlo, Ohi, Olo);
    out_gemm<<<dim3(128, 4), dim3(256), 0, stream>>>(WhiO, WloO, Ohi, Olo, outb, x, out);
}

// Round 4
// 324.597 us; speedup vs baseline: 1.1932x; 1.1932x over previous
//
#include <hip/hip_runtime.h>

#define BATCH 16
#define CDIM 512
#define SEQ 1024
#define NHEAD 4
#define HDIM 128
#define NPB (CDIM*SEQ)
#define GN_EPS 1e-5f
#define ATT_SCALE 0.08838834764831845f
#define MQ (BATCH*SEQ)        // 16384 rows
#define NQKV (3*CDIM)         // 1536

typedef __attribute__((ext_vector_type(8))) short bf16x8;
typedef __attribute__((ext_vector_type(4))) float f32x4;

__device__ __forceinline__ unsigned short f2bf(float f) {
    unsigned int u = __float_as_uint(f);
    unsigned int r = (u + 0x7fffu + ((u >> 16) & 1u)) >> 16;
    return (unsigned short)r;
}
__device__ __forceinline__ float bf2f(unsigned short h) {
    return __uint_as_float(((unsigned int)h) << 16);
}
__device__ __forceinline__ void gld16(const unsigned short* g, unsigned short* l) {
    __builtin_amdgcn_global_load_lds(
        (const __attribute__((address_space(1))) void*)g,
        (__attribute__((address_space(3))) void*)l, 16, 0, 0);
}
// LDS 16B-unit XOR swizzle: tile rows are 64B (32 bf16), unit g in 0..3.
// read unit for logical (row, g):  g ^ ((row>>1)&3)
#define SWZ(row, g) ((g) ^ (((row) >> 1) & 3))
// staging: lane l (linear dest) must fetch logical chunk ((l&3) ^ ((l>>3)&3))
#define SCHK(l) ((((l) & 3) ^ (((l) >> 3) & 3)) * 8)

// ---------------------------------------------------------------------------
// K1: GroupNorm stats (sum, sumsq per batch)
// ---------------------------------------------------------------------------
__global__ __launch_bounds__(256) void gn_stats(const float* __restrict__ x,
                                                float* __restrict__ stats) {
    int b = blockIdx.x >> 4;
    int part = blockIdx.x & 15;
    const float4* xp = (const float4*)(x + (size_t)b*NPB + (size_t)part*(NPB/16));
    float sum = 0.f, ssq = 0.f;
#pragma unroll
    for (int i = 0; i < 32; ++i) {
        float4 v = xp[threadIdx.x + i*256];
        sum += v.x + v.y + v.z + v.w;
        ssq += v.x*v.x + v.y*v.y + v.z*v.z + v.w*v.w;
    }
#pragma unroll
    for (int off = 1; off < 64; off <<= 1) {
        sum += __shfl_xor(sum, off);
        ssq += __shfl_xor(ssq, off);
    }
    __shared__ float ls[8];
    int wave = threadIdx.x >> 6, lane = threadIdx.x & 63;
    if (lane == 0) { ls[wave*2] = sum; ls[wave*2+1] = ssq; }
    __syncthreads();
    if (threadIdx.x == 0) {
        atomicAdd(&stats[b*2+0], ls[0]+ls[2]+ls[4]+ls[6]);
        atomicAdd(&stats[b*2+1], ls[1]+ls[3]+ls[5]+ls[7]);
    }
}

// ---------------------------------------------------------------------------
// K2: split fp32 weights into bf16 hi/lo
// ---------------------------------------------------------------------------
__global__ __launch_bounds__(256) void split_w(const float* __restrict__ in,
                                               unsigned short* __restrict__ hi,
                                               unsigned short* __restrict__ lo) {
    int i = blockIdx.x*256 + threadIdx.x;
    float4 v = ((const float4*)in)[i];
    ushort4 h, l;
    h.x = f2bf(v.x); l.x = f2bf(v.x - bf2f(h.x));
    h.y = f2bf(v.y); l.y = f2bf(v.y - bf2f(h.y));
    h.z = f2bf(v.z); l.z = f2bf(v.z - bf2f(h.z));
    h.w = f2bf(v.w); l.w = f2bf(v.w - bf2f(h.w));
    ((ushort4*)hi)[i] = h;
    ((ushort4*)lo)[i] = l;
}

// ---------------------------------------------------------------------------
// K3: A = GroupNorm(x) transposed to [b*s][c], split hi/lo
// ---------------------------------------------------------------------------
__global__ __launch_bounds__(256) void prep_a(const float* __restrict__ x,
                                              const float* __restrict__ stats,
                                              const float* __restrict__ gnw,
                                              const float* __restrict__ gnb,
                                              unsigned short* __restrict__ Ahi,
                                              unsigned short* __restrict__ Alo) {
    __shared__ float Ls[32][33];
    const int b = blockIdx.z;
    const int c0 = blockIdx.y * 32;
    const int s0 = blockIdx.x * 32;
    const int tx = threadIdx.x & 31, ty = threadIdx.x >> 5;
    float sum = stats[b*2+0], ssq = stats[b*2+1];
    float mean = sum * (1.f/NPB);
    float var  = ssq * (1.f/NPB) - mean*mean;
    float istd = rsqrtf(var + GN_EPS);
#pragma unroll
    for (int i = 0; i < 4; ++i) {
        int cc = ty + 8*i;
        Ls[cc][tx] = x[((size_t)b*CDIM + c0 + cc)*SEQ + s0 + tx];
    }
    __syncthreads();
    int c = c0 + tx;
    float g  = gnw[c] * istd;
    float sh = gnb[c] - mean * g;
#pragma unroll
    for (int i = 0; i < 4; ++i) {
        int ss = ty + 8*i;
        float v = Ls[tx][ss] * g + sh;
        unsigned short h = f2bf(v);
        size_t idx = ((size_t)b*SEQ + s0 + ss)*CDIM + c;
        Ahi[idx] = h;
        Alo[idx] = f2bf(v - bf2f(h));
    }
}

// ---------------------------------------------------------------------------
// K4: QKV GEMM, split-bf16 MFMA, dbuf global_load_lds + XOR-swizzled LDS.
// ---------------------------------------------------------------------------
__global__ __launch_bounds__(256, 2) void gemm_qkv(
    const unsigned short* __restrict__ Ahi, const unsigned short* __restrict__ Alo,
    const unsigned short* __restrict__ Bhi, const unsigned short* __restrict__ Blo,
    const float* __restrict__ bias,
    unsigned short* __restrict__ Chi, unsigned short* __restrict__ Clo)
{
    __shared__ __align__(16) unsigned short As[2][2][128][32];
    __shared__ __align__(16) unsigned short Bs[2][2][128][32];
    const int bid = blockIdx.x;
    const int xcd = bid & 7, tt = bid >> 3;
    const int m0 = (xcd*16 + (tt & 15)) * 128;     // 128 m-tiles, grouped per XCD
    const int n0 = (tt >> 4) * 128;                // 12 n-tiles
    const int t = threadIdx.x;
    const int w = t >> 6, l = t & 63, g = l >> 4, lm = l & 15;
    const int wm = (w & 1) * 64, wn = (w >> 1) * 64;
    f32x4 acc[4][4] = {};

    const unsigned short* src = (w==0)?Ahi:(w==1)?Alo:(w==2)?Bhi:Blo;
    const int rb = (w < 2) ? m0 : n0;
    const int srow = l >> 2, schk = SCHK(l);

    auto stage = [&](int bb, int k0) {
        unsigned short (*dst)[32] = (w==0)?As[bb][0]:(w==1)?As[bb][1]:(w==2)?Bs[bb][0]:Bs[bb][1];
#pragma unroll
        for (int i = 0; i < 8; ++i)
            gld16(src + (size_t)(rb + i*16 + srow)*CDIM + k0 + schk, &dst[i*16][0]);
    };

    stage(0, 0);
    __syncthreads();
    int buf = 0;
    for (int ks = 0; ks < 16; ++ks) {
        if (ks < 15) stage(buf ^ 1, (ks + 1) * 32);
        bf16x8 ah[4], al[4], bh[4], bl[4];
#pragma unroll
        for (int mi = 0; mi < 4; ++mi) {
            int row = wm + mi*16 + lm;
            ah[mi] = *(const bf16x8*)&As[buf][0][row][SWZ(row, g)*8];
            al[mi] = *(const bf16x8*)&As[buf][1][row][SWZ(row, g)*8];
        }
#pragma unroll
        for (int ni = 0; ni < 4; ++ni) {
            int row = wn + ni*16 + lm;
            bh[ni] = *(const bf16x8*)&Bs[buf][0][row][SWZ(row, g)*8];
            bl[ni] = *(const bf16x8*)&Bs[buf][1][row][SWZ(row, g)*8];
        }
#pragma unroll
        for (int mi = 0; mi < 4; ++mi)
#pragma unroll
            for (int ni = 0; ni < 4; ++ni) {
                acc[mi][ni] = __builtin_amdgcn_mfma_f32_16x16x32_bf16(ah[mi], bh[ni], acc[mi][ni], 0, 0, 0);
                acc[mi][ni] = __builtin_amdgcn_mfma_f32_16x16x32_bf16(ah[mi], bl[ni], acc[mi][ni], 0, 0, 0);
                acc[mi][ni] = __builtin_amdgcn_mfma_f32_16x16x32_bf16(al[mi], bh[ni], acc[mi][ni], 0, 0, 0);
            }
        if (ks < 15) { __syncthreads(); buf ^= 1; }
    }
#pragma unroll
    for (int mi = 0; mi < 4; ++mi)
#pragma unroll
        for (int ni = 0; ni < 4; ++ni) {
            int n = n0 + wn + ni*16 + lm;
            float bv = bias[n];
#pragma unroll
            for (int r = 0; r < 4; ++r) {
                int m = m0 + wm + mi*16 + 4*g + r;
                float v = acc[mi][ni][r] + bv;
                unsigned short h = f2bf(v);
                size_t idx = (size_t)m*NQKV + n;
                Chi[idx] = h;
                Clo[idx] = f2bf(v - bf2f(h));
            }
        }
}

// ---------------------------------------------------------------------------
// K5: transpose V-part of QKV -> VT[b][h][d][s], bf16 hi/lo
// ---------------------------------------------------------------------------
__global__ __launch_bounds__(256) void prep_vt(
    const unsigned short* __restrict__ QKVhi, const unsigned short* __restrict__ QKVlo,
    unsigned short* __restrict__ VThi, unsigned short* __restrict__ VTlo)
{
    __shared__ unsigned short Ts[2][32][34];
    const int s0 = blockIdx.x * 32;
    const int d0 = blockIdx.y * 32;
    const int bh = blockIdx.z;
    const int b = bh >> 2, h = bh & 3;
    const int tx = threadIdx.x & 31, ty = threadIdx.x >> 5;
#pragma unroll
    for (int i = 0; i < 4; ++i) {
        int ss = ty + 8*i;
        size_t src = ((size_t)b*SEQ + s0 + ss)*NQKV + 2*CDIM + h*HDIM + d0 + tx;
        Ts[0][ss][tx] = QKVhi[src];
        Ts[1][ss][tx] = QKVlo[src];
    }
    __syncthreads();
#pragma unroll
    for (int i = 0; i < 4; ++i) {
        int dd = ty + 8*i;
        size_t dst = ((size_t)bh*HDIM + d0 + dd)*SEQ + s0 + tx;
        VThi[dst] = Ts[0][tx][dd];
        VTlo[dst] = Ts[1][tx][dd];
    }
}

// ---------------------------------------------------------------------------
// K6: flash attention, split-bf16 MFMA.
// 8 waves (512 thr), 256 q-rows/block, grid 256 XCD-grouped by (b,h).
// Fixed-max softmax (scores bounded), l via ones-MFMA. K/V double-buffered
// via global_load_lds with XOR-swizzle.
// ---------------------------------------------------------------------------
__global__ __launch_bounds__(512, 2) void attn(
    const unsigned short* __restrict__ QKVhi, const unsigned short* __restrict__ QKVlo,
    const unsigned short* __restrict__ VThi,  const unsigned short* __restrict__ VTlo,
    unsigned short* __restrict__ Ohi, unsigned short* __restrict__ Olo)
{
    __shared__ __align__(16) unsigned short Ks[2][2][4][32][32]; // [buf][hl][kb][kv][k]
    __shared__ __align__(16) unsigned short Vs[2][2][128][32];   // [buf][hl][d][kv]
    __shared__ __align__(16) unsigned short Ps[8][2][32][40];
    const int bid = blockIdx.x;
    const int xcd = bid & 7, mm = bid >> 3;
    const int bh = xcd*8 + (mm & 7);               // 4 q-blocks of a bh share an XCD
    const int qt = mm >> 3;
    const int b = bh >> 2, h = bh & 3;
    const int t = threadIdx.x;
    const int w = t >> 6, l = t & 63, g = l >> 4, lm = l & 15;
    const int mq = b*SEQ + qt*256 + w*32;
    const int srow = l >> 2, schk = SCHK(l);

    bf16x8 qh[2][4], ql[2][4];
#pragma unroll
    for (int mi = 0; mi < 2; ++mi)
#pragma unroll
        for (int kb = 0; kb < 4; ++kb) {
            size_t idx = (size_t)(mq + mi*16 + lm)*NQKV + h*HDIM + kb*32 + g*8;
            qh[mi][kb] = *(const bf16x8*)&QKVhi[idx];
            ql[mi][kb] = *(const bf16x8*)&QKVlo[idx];
        }

    const bf16x8 vone = {0x3F80,0x3F80,0x3F80,0x3F80,0x3F80,0x3F80,0x3F80,0x3F80};
    f32x4 oacc[2][8] = {};
    f32x4 lsum[2] = {};

    // 32 loads/tile flat-list: [0,16) K (hl,kb,half), [16,32) V (hl, d-block)
    auto stage = [&](int bb, int kt) {
#pragma unroll
        for (int j = 0; j < 4; ++j) {
            int gidx = w*4 + j;
            if (gidx < 16) {
                int hl = gidx >> 3, kb = (gidx >> 1) & 3, half = gidx & 1;
                const unsigned short* s = hl ? QKVlo : QKVhi;
                gld16(s + (size_t)(b*SEQ + kt*32 + half*16 + srow)*NQKV + CDIM + h*HDIM + kb*32 + schk,
                      &Ks[bb][hl][kb][half*16][0]);
            } else {
                int v = gidx - 16; int hl = v >> 3, i = v & 7;
                const unsigned short* s = hl ? VTlo : VThi;
                gld16(s + ((size_t)bh*HDIM + i*16 + srow)*SEQ + kt*32 + schk,
                      &Vs[bb][hl][i*16][0]);
            }
        }
    };

    stage(0, 0);
    __syncthreads();
    int buf = 0;
    for (int kt = 0; kt < 32; ++kt) {
        if (kt < 31) stage(buf ^ 1, kt + 1);

        // QK^T : S[32 q][32 kv]
        f32x4 sacc[2][2] = {};
#pragma unroll
        for (int kb = 0; kb < 4; ++kb) {
            bf16x8 kh[2], kl[2];
#pragma unroll
            for (int nf = 0; nf < 2; ++nf) {
                int row = nf*16 + lm;
                kh[nf] = *(const bf16x8*)&Ks[buf][0][kb][row][SWZ(row, g)*8];
                kl[nf] = *(const bf16x8*)&Ks[buf][1][kb][row][SWZ(row, g)*8];
            }
#pragma unroll
            for (int mi = 0; mi < 2; ++mi)
#pragma unroll
                for (int nf = 0; nf < 2; ++nf) {
                    sacc[mi][nf] = __builtin_amdgcn_mfma_f32_16x16x32_bf16(qh[mi][kb], kh[nf], sacc[mi][nf], 0, 0, 0);
                    sacc[mi][nf] = __builtin_amdgcn_mfma_f32_16x16x32_bf16(qh[mi][kb], kl[nf], sacc[mi][nf], 0, 0, 0);
                    sacc[mi][nf] = __builtin_amdgcn_mfma_f32_16x16x32_bf16(ql[mi][kb], kh[nf], sacc[mi][nf], 0, 0, 0);
                }
        }
        // fixed-max softmax: P = exp(s*scale) (scores bounded, fp32 safe)
#pragma unroll
        for (int mi = 0; mi < 2; ++mi)
#pragma unroll
            for (int nf = 0; nf < 2; ++nf)
#pragma unroll
                for (int r = 0; r < 4; ++r) {
                    float p = __expf(sacc[mi][nf][r] * ATT_SCALE);
                    unsigned short ph = f2bf(p);
                    int q = mi*16 + 4*g + r, kv = nf*16 + lm;
                    Ps[w][0][q][kv] = ph;
                    Ps[w][1][q][kv] = f2bf(p - bf2f(ph));
                }
        // same-wave LDS write->read fence (rule #18)
        asm volatile("s_waitcnt lgkmcnt(0)" ::: "memory");
        __builtin_amdgcn_sched_barrier(0);
        bf16x8 ph[2], pl[2];
#pragma unroll
        for (int mi = 0; mi < 2; ++mi) {
            ph[mi] = *(const bf16x8*)&Ps[w][0][mi*16 + lm][g*8];
            pl[mi] = *(const bf16x8*)&Ps[w][1][mi*16 + lm][g*8];
        }
        // row sums via ones-MFMA (replicated over cols)
#pragma unroll
        for (int mi = 0; mi < 2; ++mi) {
            lsum[mi] = __builtin_amdgcn_mfma_f32_16x16x32_bf16(ph[mi], vone, lsum[mi], 0, 0, 0);
            lsum[mi] = __builtin_amdgcn_mfma_f32_16x16x32_bf16(pl[mi], vone, lsum[mi], 0, 0, 0);
        }
        // PV
#pragma unroll
        for (int nd = 0; nd < 8; ++nd) {
            int row = nd*16 + lm;
            bf16x8 vh = *(const bf16x8*)&Vs[buf][0][row][SWZ(row, g)*8];
            bf16x8 vl = *(const bf16x8*)&Vs[buf][1][row][SWZ(row, g)*8];
#pragma unroll
            for (int mi = 0; mi < 2; ++mi) {
                oacc[mi][nd] = __builtin_amdgcn_mfma_f32_16x16x32_bf16(ph[mi], vh, oacc[mi][nd], 0, 0, 0);
                oacc[mi][nd] = __builtin_amdgcn_mfma_f32_16x16x32_bf16(ph[mi], vl, oacc[mi][nd], 0, 0, 0);
                oacc[mi][nd] = __builtin_amdgcn_mfma_f32_16x16x32_bf16(pl[mi], vh, oacc[mi][nd], 0, 0, 0);
            }
        }
        if (kt < 31) { __syncthreads(); buf ^= 1; }
    }
#pragma unroll
    for (int mi = 0; mi < 2; ++mi)
#pragma unroll
        for (int r = 0; r < 4; ++r) {
            float inv = 1.f / lsum[mi][r];
#pragma unroll
            for (int nd = 0; nd < 8; ++nd) {
                float v = oacc[mi][nd][r] * inv;
                int m = mq + mi*16 + 4*g + r;
                int col = h*HDIM + nd*16 + lm;
                unsigned short hh = f2bf(v);
                size_t idx = (size_t)m*CDIM + col;
                Ohi[idx] = hh;
                Olo[idx] = f2bf(v - bf2f(hh));
            }
        }
}

// ---------------------------------------------------------------------------
// K7: output projection (transposed), dbuf + swizzle; bias + residual fused.
// ---------------------------------------------------------------------------
__global__ __launch_bounds__(256, 2) void out_gemm(
    const unsigned short* __restrict__ Whi, const unsigned short* __restrict__ Wlo,
    const unsigned short* __restrict__ Ohi, const unsigned short* __restrict__ Olo,
    const float* __restrict__ bias, const float* __restrict__ x,
    float* __restrict__ out)
{
    __shared__ __align__(16) unsigned short As[2][2][128][32];
    __shared__ __align__(16) unsigned short Bs[2][2][128][32];
    const int bid = blockIdx.x;
    const int xcd = bid & 7, tt = bid >> 3;
    const int m0 = (xcd*16 + (tt & 15)) * 128;     // 128 m-tiles grouped per XCD
    const int c0 = (tt >> 4) * 128;                // 4 c-tiles
    const int t = threadIdx.x;
    const int w = t >> 6, l = t & 63, g = l >> 4, lm = l & 15;
    const int wc = (w & 1) * 64, wn = (w >> 1) * 64;
    f32x4 acc[4][4] = {};

    const unsigned short* src = (w==0)?Whi:(w==1)?Wlo:(w==2)?Ohi:Olo;
    const int rb = (w < 2) ? c0 : m0;
    const int srow = l >> 2, schk = SCHK(l);

    auto stage = [&](int bb, int k0) {
        unsigned short (*dst)[32] = (w==0)?As[bb][0]:(w==1)?As[bb][1]:(w==2)?Bs[bb][0]:Bs[bb][1];
#pragma unroll
        for (int i = 0; i < 8; ++i)
            gld16(src + (size_t)(rb + i*16 + srow)*CDIM + k0 + schk, &dst[i*16][0]);
    };

    stage(0, 0);
    __syncthreads();
    int buf = 0;
    for (int ks = 0; ks < 16; ++ks) {
        if (ks < 15) stage(buf ^ 1, (ks + 1) * 32);
        bf16x8 ah[4], al[4], bh[4], bl[4];
#pragma unroll
        for (int mi = 0; mi < 4; ++mi) {
            int row = wc + mi*16 + lm;
            ah[mi] = *(const bf16x8*)&As[buf][0][row][SWZ(row, g)*8];
            al[mi] = *(const bf16x8*)&As[buf][1][row][SWZ(row, g)*8];
        }
#pragma unroll
        for (int ni = 0; ni < 4; ++ni) {
            int row = wn + ni*16 + lm;
            bh[ni] = *(const bf16x8*)&Bs[buf][0][row][SWZ(row, g)*8];
            bl[ni] = *(const bf16x8*)&Bs[buf][1][row][SWZ(row, g)*8];
        }
#pragma unroll
        for (int mi = 0; mi < 4; ++mi)
#pragma unroll
            for (int ni = 0; ni < 4; ++ni) {
                acc[mi][ni] = __builtin_amdgcn_mfma_f32_16x16x32_bf16(ah[mi], bh[ni], acc[mi][ni], 0, 0, 0);
                acc[mi][ni] = __builtin_amdgcn_mfma_f32_16x16x32_bf16(ah[mi], bl[ni], acc[mi][ni], 0, 0, 0);
                acc[mi][ni] = __builtin_amdgcn_mfma_f32_16x16x32_bf16(al[mi], bh[ni], acc[mi][ni], 0, 0, 0);
            }
        if (ks < 15) { __syncthreads(); buf ^= 1; }
    }
#pragma unroll
    for (int mi = 0; mi < 4; ++mi)
#pragma unroll
        for (int r = 0; r < 4; ++r) {
            int c = c0 + wc + mi*16 + 4*g + r;
            float bv = bias[c];
#pragma unroll
            for (int ni = 0; ni < 4; ++ni) {
                int m = m0 + wn + ni*16 + lm;
                int bb = m >> 10, s = m & 1023;
                size_t idx = ((size_t)bb*CDIM + c)*SEQ + s;
                out[idx] = x[idx] + acc[mi][ni][r] + bv;
            }
        }
}

// ---------------------------------------------------------------------------
extern "C" void kernel_launch(void* const* d_in, const int* in_sizes, int n_in,
                              void* d_out, int out_size, void* d_ws, size_t ws_size,
                              hipStream_t stream) {
    const float* x    = (const float*)d_in[0];
    const float* gnw  = (const float*)d_in[1];
    const float* gnb  = (const float*)d_in[2];
    const float* qkvw = (const float*)d_in[3];
    const float* qkvb = (const float*)d_in[4];
    const float* outw = (const float*)d_in[5];
    const float* outb = (const float*)d_in[6];
    float* out = (float*)d_out;

    char* wsp = (char*)d_ws;
    size_t off = 0;
    float* stats = (float*)wsp;                 off += 256;
    unsigned short* WhiQ = (unsigned short*)(wsp+off); off += (size_t)NQKV*CDIM*2;
    unsigned short* WloQ = (unsigned short*)(wsp+off); off += (size_t)NQKV*CDIM*2;
    unsigned short* WhiO = (unsigned short*)(wsp+off); off += (size_t)CDIM*CDIM*2;
    unsigned short* WloO = (unsigned short*)(wsp+off); off += (size_t)CDIM*CDIM*2;
    unsigned short* Ahi  = (unsigned short*)(wsp+off); off += (size_t)MQ*CDIM*2;
    unsigned short* Alo  = (unsigned short*)(wsp+off); off += (size_t)MQ*CDIM*2;
    unsigned short* Qhi  = (unsigned short*)(wsp+off); off += (size_t)MQ*NQKV*2;
    unsigned short* Qlo  = (unsigned short*)(wsp+off); off += (size_t)MQ*NQKV*2;
    unsigned short* VThi = (unsigned short*)(wsp+off); off += (size_t)MQ*CDIM*2;
    unsigned short* VTlo = (unsigned short*)(wsp+off); off += (size_t)MQ*CDIM*2;
    unsigned short* Ohi = Ahi;   // A dead after gemm_qkv
    unsigned short* Olo = Alo;

    hipMemsetAsync(stats, 0, 256, stream);
    gn_stats<<<dim3(256), dim3(256), 0, stream>>>(x, stats);
    split_w<<<dim3((NQKV*CDIM)/1024), dim3(256), 0, stream>>>(qkvw, WhiQ, WloQ);
    split_w<<<dim3((CDIM*CDIM)/1024), dim3(256), 0, stream>>>(outw, WhiO, WloO);
    prep_a<<<dim3(32, 16, 16), dim3(256), 0, stream>>>(x, stats, gnw, gnb, Ahi, Alo);
    gemm_qkv<<<dim3(1536), dim3(256), 0, stream>>>(Ahi, Alo, WhiQ, WloQ, qkvb, Qhi, Qlo);
    prep_vt<<<dim3(32, 4, 64), dim3(256), 0, stream>>>(Qhi, Qlo, VThi, VTlo);
    attn<<<dim3(256), dim3(512), 0, stream>>>(Qhi, Qlo, VThi, VTlo, Ohi, Olo);
    out_gemm<<<dim3(512), dim3(256), 0, stream>>>(WhiO, WloO, Ohi, Olo, outb, x, out);
}

// Round 7
// 224.307 us; speedup vs baseline: 1.7267x; 1.4471x over previous
//
#include <hip/hip_runtime.h>

#define BATCH 16
#define CDIM 512
#define SEQ 1024
#define NHEAD 4
#define HDIM 128
#define NPB (CDIM*SEQ)
#define GN_EPS 1e-5f
#define ATT_SCALE 0.08838834764831845f
#define EXP_SHIFT 4.0f
#define MQ (BATCH*SEQ)        // 16384 rows
#define NQKV (3*CDIM)         // 1536

typedef __attribute__((ext_vector_type(8))) short bf16x8;
typedef __attribute__((ext_vector_type(8))) _Float16 f16x8;
typedef __attribute__((ext_vector_type(4))) float f32x4;

__device__ __forceinline__ unsigned short f2bf(float f) {
    unsigned int u = __float_as_uint(f);
    unsigned int r = (u + 0x7fffu + ((u >> 16) & 1u)) >> 16;
    return (unsigned short)r;
}
__device__ __forceinline__ float bf2f(unsigned short h) {
    return __uint_as_float(((unsigned int)h) << 16);
}
__device__ __forceinline__ unsigned short f2h(float f) {
    union { _Float16 h; unsigned short u; } cv;
    cv.h = (_Float16)f;
    return cv.u;
}
__device__ __forceinline__ void gld16(const unsigned short* g, unsigned short* l) {
    __builtin_amdgcn_global_load_lds(
        (const __attribute__((address_space(1))) void*)g,
        (__attribute__((address_space(3))) void*)l, 16, 0, 0);
}
// LDS 16B-unit XOR swizzle for 64B rows (4 units): read unit g^((row>>1)&3);
// staging lane l fetches logical chunk (l&3)^((l>>3)&3) into linear dest.
#define SWZ(row, g) ((g) ^ (((row) >> 1) & 3))
#define SCHK(l) ((((l) & 3) ^ (((l) >> 3) & 3)) * 8)

// ---------------------------------------------------------------------------
// K1: GroupNorm stats (sum, sumsq per batch)
// ---------------------------------------------------------------------------
__global__ __launch_bounds__(256) void gn_stats(const float* __restrict__ x,
                                                float* __restrict__ stats) {
    int b = blockIdx.x >> 4;
    int part = blockIdx.x & 15;
    const float4* xp = (const float4*)(x + (size_t)b*NPB + (size_t)part*(NPB/16));
    float sum = 0.f, ssq = 0.f;
#pragma unroll
    for (int i = 0; i < 32; ++i) {
        float4 v = xp[threadIdx.x + i*256];
        sum += v.x + v.y + v.z + v.w;
        ssq += v.x*v.x + v.y*v.y + v.z*v.z + v.w*v.w;
    }
#pragma unroll
    for (int off = 1; off < 64; off <<= 1) {
        sum += __shfl_xor(sum, off);
        ssq += __shfl_xor(ssq, off);
    }
    __shared__ float ls[8];
    int wave = threadIdx.x >> 6, lane = threadIdx.x & 63;
    if (lane == 0) { ls[wave*2] = sum; ls[wave*2+1] = ssq; }
    __syncthreads();
    if (threadIdx.x == 0) {
        atomicAdd(&stats[b*2+0], ls[0]+ls[2]+ls[4]+ls[6]);
        atomicAdd(&stats[b*2+1], ls[1]+ls[3]+ls[5]+ls[7]);
    }
}

// ---------------------------------------------------------------------------
// K2a: cast fp32 weights to fp16 (qkv_w)     K2b: split bf16 hi/lo (out_w)
// ---------------------------------------------------------------------------
__global__ __launch_bounds__(256) void cast_w(const float* __restrict__ in,
                                              unsigned short* __restrict__ hi) {
    int i = blockIdx.x*256 + threadIdx.x;
    float4 v = ((const float4*)in)[i];
    ushort4 h;
    h.x = f2h(v.x); h.y = f2h(v.y); h.z = f2h(v.z); h.w = f2h(v.w);
    ((ushort4*)hi)[i] = h;
}
__global__ __launch_bounds__(256) void split_w(const float* __restrict__ in,
                                               unsigned short* __restrict__ hi,
                                               unsigned short* __restrict__ lo) {
    int i = blockIdx.x*256 + threadIdx.x;
    float4 v = ((const float4*)in)[i];
    ushort4 h, l;
    h.x = f2bf(v.x); l.x = f2bf(v.x - bf2f(h.x));
    h.y = f2bf(v.y); l.y = f2bf(v.y - bf2f(h.y));
    h.z = f2bf(v.z); l.z = f2bf(v.z - bf2f(h.z));
    h.w = f2bf(v.w); l.w = f2bf(v.w - bf2f(h.w));
    ((ushort4*)hi)[i] = h;
    ((ushort4*)lo)[i] = l;
}

// ---------------------------------------------------------------------------
// K3: A = GroupNorm(x) transposed to [b*s][c], fp16
// ---------------------------------------------------------------------------
__global__ __launch_bounds__(256) void prep_a(const float* __restrict__ x,
                                              const float* __restrict__ stats,
                                              const float* __restrict__ gnw,
                                              const float* __restrict__ gnb,
                                              unsigned short* __restrict__ Ahi) {
    __shared__ float Ls[32][33];
    const int b = blockIdx.z;
    const int c0 = blockIdx.y * 32;
    const int s0 = blockIdx.x * 32;
    const int tx = threadIdx.x & 31, ty = threadIdx.x >> 5;
    float sum = stats[b*2+0], ssq = stats[b*2+1];
    float mean = sum * (1.f/NPB);
    float var  = ssq * (1.f/NPB) - mean*mean;
    float istd = rsqrtf(var + GN_EPS);
#pragma unroll
    for (int i = 0; i < 4; ++i) {
        int cc = ty + 8*i;
        Ls[cc][tx] = x[((size_t)b*CDIM + c0 + cc)*SEQ + s0 + tx];
    }
    __syncthreads();
    int c = c0 + tx;
    float g  = gnw[c] * istd;
    float sh = gnb[c] - mean * g;
#pragma unroll
    for (int i = 0; i < 4; ++i) {
        int ss = ty + 8*i;
        float v = Ls[tx][ss] * g + sh;
        Ahi[((size_t)b*SEQ + s0 + ss)*CDIM + c] = f2h(v);
    }
}

// ---------------------------------------------------------------------------
// K4: QKV GEMM, single-fp16 MFMA, dbuf global_load_lds + XOR swizzle.
// C[m][n] = A[m][k] . W[n][k] + bias, fp16 out.
// ---------------------------------------------------------------------------
__global__ __launch_bounds__(256, 2) void gemm_qkv(
    const unsigned short* __restrict__ Ahi, const unsigned short* __restrict__ Bhi,
    const float* __restrict__ bias, unsigned short* __restrict__ Chi)
{
    __shared__ __align__(16) unsigned short As[2][128][32];
    __shared__ __align__(16) unsigned short Bs[2][128][32];
    const int bid = blockIdx.x;
    const int xcd = bid & 7, tt = bid >> 3;
    const int m0 = (xcd*16 + (tt & 15)) * 128;
    const int n0 = (tt >> 4) * 128;
    const int t = threadIdx.x;
    const int w = t >> 6, l = t & 63, g = l >> 4, lm = l & 15;
    const int wm = (w & 1) * 64, wn = (w >> 1) * 64;
    f32x4 acc[4][4] = {};

    const unsigned short* src = (w < 2) ? Ahi : Bhi;
    const int rb = ((w < 2) ? m0 : n0) + (w & 1) * 64;
    const int srow = l >> 2, schk = SCHK(l);

    auto stage = [&](int bb, int k0) {
        unsigned short (*dst)[32] = ((w < 2) ? As[bb] : Bs[bb]) + (w & 1) * 64;
#pragma unroll
        for (int i = 0; i < 4; ++i)
            gld16(src + (size_t)(rb + i*16 + srow)*CDIM + k0 + schk, &dst[i*16][0]);
    };

    stage(0, 0);
    __syncthreads();
    int buf = 0;
    for (int ks = 0; ks < 16; ++ks) {
        if (ks < 15) stage(buf ^ 1, (ks + 1) * 32);
        f16x8 ah[4], bh[4];
#pragma unroll
        for (int mi = 0; mi < 4; ++mi) {
            int row = wm + mi*16 + lm;
            ah[mi] = *(const f16x8*)&As[buf][row][SWZ(row, g)*8];
        }
#pragma unroll
        for (int ni = 0; ni < 4; ++ni) {
            int row = wn + ni*16 + lm;
            bh[ni] = *(const f16x8*)&Bs[buf][row][SWZ(row, g)*8];
        }
#pragma unroll
        for (int mi = 0; mi < 4; ++mi)
#pragma unroll
            for (int ni = 0; ni < 4; ++ni)
                acc[mi][ni] = __builtin_amdgcn_mfma_f32_16x16x32_f16(ah[mi], bh[ni], acc[mi][ni], 0, 0, 0);
        if (ks < 15) { __syncthreads(); buf ^= 1; }
    }
#pragma unroll
    for (int mi = 0; mi < 4; ++mi)
#pragma unroll
        for (int ni = 0; ni < 4; ++ni) {
            int n = n0 + wn + ni*16 + lm;
            float bv = bias[n];
#pragma unroll
            for (int r = 0; r < 4; ++r) {
                int m = m0 + wm + mi*16 + 4*g + r;
                Chi[(size_t)m*NQKV + n] = f2h(acc[mi][ni][r] + bv);
            }
        }
}

// ---------------------------------------------------------------------------
// K5: transpose V-part of QKV -> VT[b][h][d][s] (bit-agnostic ushort moves)
// ---------------------------------------------------------------------------
__global__ __launch_bounds__(256) void prep_vt(
    const unsigned short* __restrict__ QKVhi, unsigned short* __restrict__ VThi)
{
    __shared__ unsigned short Ts[32][34];
    const int s0 = blockIdx.x * 32;
    const int d0 = blockIdx.y * 32;
    const int bh = blockIdx.z;
    const int b = bh >> 2, h = bh & 3;
    const int tx = threadIdx.x & 31, ty = threadIdx.x >> 5;
#pragma unroll
    for (int i = 0; i < 4; ++i) {
        int ss = ty + 8*i;
        Ts[ss][tx] = QKVhi[((size_t)b*SEQ + s0 + ss)*NQKV + 2*CDIM + h*HDIM + d0 + tx];
    }
    __syncthreads();
#pragma unroll
    for (int i = 0; i < 4; ++i) {
        int dd = ty + 8*i;
        VThi[((size_t)bh*HDIM + d0 + dd)*SEQ + s0 + tx] = Ts[tx][dd];
    }
}

// ---------------------------------------------------------------------------
// K6: flash attention, single-fp16 MFMA. 4 waves / 128 q-rows per block,
// grid 512 XCD-grouped by (b,h). Shifted fixed-max softmax
// P = exp(s*scale - 4) (cancels in quotient; bounds P for fp16).
// l via ones-MFMA. K/V dbuf global_load_lds + XOR swizzle. O out bf16 hi/lo.
// ---------------------------------------------------------------------------
__global__ __launch_bounds__(256, 2) void attn(
    const unsigned short* __restrict__ QKVhi, const unsigned short* __restrict__ VThi,
    unsigned short* __restrict__ Ohi, unsigned short* __restrict__ Olo)
{
    __shared__ __align__(16) unsigned short Ks[2][4][32][32]; // [buf][kb][kv][k]
    __shared__ __align__(16) unsigned short Vs[2][128][32];   // [buf][d][kv]
    __shared__ __align__(16) unsigned short Ps[4][32][40];
    const int bid = blockIdx.x;
    const int xcd = bid & 7, rest = bid >> 3;
    const int bh = xcd*8 + (rest & 7);
    const int qt = rest >> 3;                       // 0..7
    const int b = bh >> 2, h = bh & 3;
    const int t = threadIdx.x;
    const int w = t >> 6, l = t & 63, g = l >> 4, lm = l & 15;
    const int mq = b*SEQ + qt*128 + w*32;
    const int srow = l >> 2, schk = SCHK(l);

    f16x8 qh[2][4];
#pragma unroll
    for (int mi = 0; mi < 2; ++mi)
#pragma unroll
        for (int kb = 0; kb < 4; ++kb)
            qh[mi][kb] = *(const f16x8*)&QKVhi[(size_t)(mq + mi*16 + lm)*NQKV + h*HDIM + kb*32 + g*8];

    const f16x8 vone = {(_Float16)1.f,(_Float16)1.f,(_Float16)1.f,(_Float16)1.f,
                        (_Float16)1.f,(_Float16)1.f,(_Float16)1.f,(_Float16)1.f};
    f32x4 oacc[2][8] = {};
    f32x4 lsum[2] = {};

    // 16 wave-loads per tile: [0,8) K (kb, half), [8,16) V d-block
    auto stage = [&](int bb, int kt) {
#pragma unroll
        for (int j = 0; j < 4; ++j) {
            int gidx = w*4 + j;
            if (gidx < 8) {
                int kb = gidx >> 1, half = gidx & 1;
                gld16(QKVhi + (size_t)(b*SEQ + kt*32 + half*16 + srow)*NQKV + CDIM + h*HDIM + kb*32 + schk,
                      &Ks[bb][kb][half*16][0]);
            } else {
                int i = gidx - 8;
                gld16(VThi + ((size_t)bh*HDIM + i*16 + srow)*SEQ + kt*32 + schk,
                      &Vs[bb][i*16][0]);
            }
        }
    };

    stage(0, 0);
    __syncthreads();
    int buf = 0;
    for (int kt = 0; kt < 32; ++kt) {
        if (kt < 31) stage(buf ^ 1, kt + 1);

        // QK^T : S[32 q][32 kv]
        f32x4 sacc[2][2] = {};
#pragma unroll
        for (int kb = 0; kb < 4; ++kb) {
            f16x8 kh[2];
#pragma unroll
            for (int nf = 0; nf < 2; ++nf) {
                int row = nf*16 + lm;
                kh[nf] = *(const f16x8*)&Ks[buf][kb][row][SWZ(row, g)*8];
            }
#pragma unroll
            for (int mi = 0; mi < 2; ++mi)
#pragma unroll
                for (int nf = 0; nf < 2; ++nf)
                    sacc[mi][nf] = __builtin_amdgcn_mfma_f32_16x16x32_f16(qh[mi][kb], kh[nf], sacc[mi][nf], 0, 0, 0);
        }
        // shifted fixed-max softmax: P = exp(s*scale - C), C cancels in O
#pragma unroll
        for (int mi = 0; mi < 2; ++mi)
#pragma unroll
            for (int nf = 0; nf < 2; ++nf)
#pragma unroll
                for (int r = 0; r < 4; ++r) {
                    float p = __expf(fmaf(sacc[mi][nf][r], ATT_SCALE, -EXP_SHIFT));
                    Ps[w][mi*16 + 4*g + r][nf*16 + lm] = f2h(p);
                }
        // same-wave LDS write->read fence (rule #18)
        asm volatile("s_waitcnt lgkmcnt(0)" ::: "memory");
        __builtin_amdgcn_sched_barrier(0);
        f16x8 ph[2];
#pragma unroll
        for (int mi = 0; mi < 2; ++mi)
            ph[mi] = *(const f16x8*)&Ps[w][mi*16 + lm][g*8];
        // row sums via ones-MFMA (replicated over cols)
#pragma unroll
        for (int mi = 0; mi < 2; ++mi)
            lsum[mi] = __builtin_amdgcn_mfma_f32_16x16x32_f16(ph[mi], vone, lsum[mi], 0, 0, 0);
        // PV
#pragma unroll
        for (int nd = 0; nd < 8; ++nd) {
            int row = nd*16 + lm;
            f16x8 vh = *(const f16x8*)&Vs[buf][row][SWZ(row, g)*8];
#pragma unroll
            for (int mi = 0; mi < 2; ++mi)
                oacc[mi][nd] = __builtin_amdgcn_mfma_f32_16x16x32_f16(ph[mi], vh, oacc[mi][nd], 0, 0, 0);
        }
        if (kt < 31) { __syncthreads(); buf ^= 1; }
    }
#pragma unroll
    for (int mi = 0; mi < 2; ++mi)
#pragma unroll
        for (int r = 0; r < 4; ++r) {
            float inv = 1.f / lsum[mi][r];
#pragma unroll
            for (int nd = 0; nd < 8; ++nd) {
                float v = oacc[mi][nd][r] * inv;
                int m = mq + mi*16 + 4*g + r;
                int col = h*HDIM + nd*16 + lm;
                unsigned short hh = f2bf(v);
                size_t idx = (size_t)m*CDIM + col;
                Ohi[idx] = hh;
                Olo[idx] = f2bf(v - bf2f(hh));
            }
        }
}

// ---------------------------------------------------------------------------
// K7: output projection (transposed), 3-term bf16 split; bias+residual fused.
// ---------------------------------------------------------------------------
__global__ __launch_bounds__(256, 2) void out_gemm(
    const unsigned short* __restrict__ Whi, const unsigned short* __restrict__ Wlo,
    const unsigned short* __restrict__ Ohi, const unsigned short* __restrict__ Olo,
    const float* __restrict__ bias, const float* __restrict__ x,
    float* __restrict__ out)
{
    __shared__ __align__(16) unsigned short As[2][2][128][32];
    __shared__ __align__(16) unsigned short Bs[2][2][128][32];
    const int bid = blockIdx.x;
    const int xcd = bid & 7, tt = bid >> 3;
    const int m0 = (xcd*16 + (tt & 15)) * 128;
    const int c0 = (tt >> 4) * 128;
    const int t = threadIdx.x;
    const int w = t >> 6, l = t & 63, g = l >> 4, lm = l & 15;
    const int wc = (w & 1) * 64, wn = (w >> 1) * 64;
    f32x4 acc[4][4] = {};

    const unsigned short* src = (w==0)?Whi:(w==1)?Wlo:(w==2)?Ohi:Olo;
    const int rb = (w < 2) ? c0 : m0;
    const int srow = l >> 2, schk = SCHK(l);

    auto stage = [&](int bb, int k0) {
        unsigned short (*dst)[32] = (w==0)?As[bb][0]:(w==1)?As[bb][1]:(w==2)?Bs[bb][0]:Bs[bb][1];
#pragma unroll
        for (int i = 0; i < 8; ++i)
            gld16(src + (size_t)(rb + i*16 + srow)*CDIM + k0 + schk, &dst[i*16][0]);
    };

    stage(0, 0);
    __syncthreads();
    int buf = 0;
    for (int ks = 0; ks < 16; ++ks) {
        if (ks < 15) stage(buf ^ 1, (ks + 1) * 32);
        bf16x8 ah[4], al[4], bh[4], bl[4];
#pragma unroll
        for (int mi = 0; mi < 4; ++mi) {
            int row = wc + mi*16 + lm;
            ah[mi] = *(const bf16x8*)&As[buf][0][row][SWZ(row, g)*8];
            al[mi] = *(const bf16x8*)&As[buf][1][row][SWZ(row, g)*8];
        }
#pragma unroll
        for (int ni = 0; ni < 4; ++ni) {
            int row = wn + ni*16 + lm;
            bh[ni] = *(const bf16x8*)&Bs[buf][0][row][SWZ(row, g)*8];
            bl[ni] = *(const bf16x8*)&Bs[buf][1][row][SWZ(row, g)*8];
        }
#pragma unroll
        for (int mi = 0; mi < 4; ++mi)
#pragma unroll
            for (int ni = 0; ni < 4; ++ni) {
                acc[mi][ni] = __builtin_amdgcn_mfma_f32_16x16x32_bf16(ah[mi], bh[ni], acc[mi][ni], 0, 0, 0);
                acc[mi][ni] = __builtin_amdgcn_mfma_f32_16x16x32_bf16(ah[mi], bl[ni], acc[mi][ni], 0, 0, 0);
                acc[mi][ni] = __builtin_amdgcn_mfma_f32_16x16x32_bf16(al[mi], bh[ni], acc[mi][ni], 0, 0, 0);
            }
        if (ks < 15) { __syncthreads(); buf ^= 1; }
    }
#pragma unroll
    for (int mi = 0; mi < 4; ++mi)
#pragma unroll
        for (int r = 0; r < 4; ++r) {
            int c = c0 + wc + mi*16 + 4*g + r;
            float bv = bias[c];
#pragma unroll
            for (int ni = 0; ni < 4; ++ni) {
                int m = m0 + wn + ni*16 + lm;
                int bb = m >> 10, s = m & 1023;
                size_t idx = ((size_t)bb*CDIM + c)*SEQ + s;
                out[idx] = x[idx] + acc[mi][ni][r] + bv;
            }
        }
}

// ---------------------------------------------------------------------------
extern "C" void kernel_launch(void* const* d_in, const int* in_sizes, int n_in,
                              void* d_out, int out_size, void* d_ws, size_t ws_size,
                              hipStream_t stream) {
    const float* x    = (const float*)d_in[0];
    const float* gnw  = (const float*)d_in[1];
    const float* gnb  = (const float*)d_in[2];
    const float* qkvw = (const float*)d_in[3];
    const float* qkvb = (const float*)d_in[4];
    const float* outw = (const float*)d_in[5];
    const float* outb = (const float*)d_in[6];
    float* out = (float*)d_out;

    char* wsp = (char*)d_ws;
    size_t off = 0;
    float* stats = (float*)wsp;                        off += 256;
    unsigned short* WhiQ = (unsigned short*)(wsp+off); off += (size_t)NQKV*CDIM*2;
    unsigned short* WhiO = (unsigned short*)(wsp+off); off += (size_t)CDIM*CDIM*2;
    unsigned short* WloO = (unsigned short*)(wsp+off); off += (size_t)CDIM*CDIM*2;
    unsigned short* Ahi  = (unsigned short*)(wsp+off); off += (size_t)MQ*CDIM*2;
    unsigned short* Qhi  = (unsigned short*)(wsp+off); off += (size_t)MQ*NQKV*2;
    unsigned short* VThi = (unsigned short*)(wsp+off); off += (size_t)MQ*CDIM*2;
    unsigned short* Olo  = (unsigned short*)(wsp+off); off += (size_t)MQ*CDIM*2;
    unsigned short* Ohi  = Ahi;   // A dead after gemm_qkv

    hipMemsetAsync(stats, 0, 256, stream);
    gn_stats<<<dim3(256), dim3(256), 0, stream>>>(x, stats);
    cast_w<<<dim3((NQKV*CDIM)/1024), dim3(256), 0, stream>>>(qkvw, WhiQ);
    split_w<<<dim3((CDIM*CDIM)/1024), dim3(256), 0, stream>>>(outw, WhiO, WloO);
    prep_a<<<dim3(32, 16, 16), dim3(256), 0, stream>>>(x, stats, gnw, gnb, Ahi);
    gemm_qkv<<<dim3(1536), dim3(256), 0, stream>>>(Ahi, WhiQ, qkvb, Qhi);
    prep_vt<<<dim3(32, 4, 64), dim3(256), 0, stream>>>(Qhi, VThi);
    attn<<<dim3(512), dim3(256), 0, stream>>>(Qhi, VThi, Ohi, Olo);
    out_gemm<<<dim3(512), dim3(256), 0, stream>>>(WhiO, WloO, Ohi, Olo, outb, x, out);
}